// Round 5
// baseline (436.210 us; speedup 1.0000x reference)
//
#include <hip/hip_runtime.h>
#include <hip/hip_bf16.h>
#include <cmath>

// ---------------- problem constants ----------------
#define T_TOKENS 4096   // 2*2048
#define DMODEL   1024
#define HDIM     2048
#define NEXP     8
#define BM 256          // M-tile (rows padded per expert to 256)
#define BK 64
#define MAXROWS 10240   // 8192 routed rows + worst-case per-expert padding to 256
#define MTILES  (MAXROWS / BM)   // 40

typedef __bf16 bf16;
typedef __bf16 bf16x8 __attribute__((ext_vector_type(8)));
typedef __bf16 bf16x4 __attribute__((ext_vector_type(4)));
typedef float  f32x4  __attribute__((ext_vector_type(4)));

__device__ inline void gload_lds16(const void* g, void* l) {
  __builtin_amdgcn_global_load_lds(
      (const __attribute__((address_space(1))) void*)g,
      (__attribute__((address_space(3))) void*)l, 16, 0, 0);
}

// ---------------- router ----------------
__global__ __launch_bounds__(256) void router_kernel(
    const float* __restrict__ x, const float* __restrict__ gw,
    bf16* __restrict__ xb, int* __restrict__ es, float* __restrict__ wsv,
    int* __restrict__ counts)
{
  int wid = threadIdx.x >> 6, lane = threadIdx.x & 63;
  int t = blockIdx.x * 4 + wid;
  if (t >= T_TOKENS) return;
  const float* xrow = x + (size_t)t * DMODEL;

  double acc[NEXP];
#pragma unroll
  for (int e = 0; e < NEXP; e++) acc[e] = 0.0;

#pragma unroll
  for (int i = 0; i < 4; i++) {
    int d0 = (i * 64 + lane) * 4;
    float4 xv = *(const float4*)(xrow + d0);
    bf16x4 o = { (bf16)xv.x, (bf16)xv.y, (bf16)xv.z, (bf16)xv.w };
    *(bf16x4*)(xb + (size_t)t * DMODEL + d0) = o;
    const float* g0 = gw + (size_t)d0 * NEXP;
    float xs[4] = { xv.x, xv.y, xv.z, xv.w };
#pragma unroll
    for (int j = 0; j < 4; j++)
#pragma unroll
      for (int e = 0; e < NEXP; e++)
        acc[e] += (double)xs[j] * (double)g0[j * NEXP + e];
  }
#pragma unroll
  for (int e = 0; e < NEXP; e++) {
    double v = acc[e];
#pragma unroll
    for (int m = 32; m >= 1; m >>= 1) v += __shfl_xor(v, m, 64);
    acc[e] = v;
  }
  if (lane == 0) {
    float l[NEXP], p[NEXP];
    float mx = -1e30f;
#pragma unroll
    for (int e = 0; e < NEXP; e++) { l[e] = (float)acc[e]; mx = fmaxf(mx, l[e]); }
    float s = 0.f;
#pragma unroll
    for (int e = 0; e < NEXP; e++) { p[e] = __expf(l[e] - mx); s += p[e]; }
#pragma unroll
    for (int e = 0; e < NEXP; e++) p[e] /= s;
    int i0 = 0;
#pragma unroll
    for (int e = 1; e < NEXP; e++) if (p[e] > p[i0]) i0 = e;
    int i1 = (i0 == 0) ? 1 : 0;
#pragma unroll
    for (int e = 0; e < NEXP; e++) if (e != i0 && p[e] > p[i1]) i1 = e;
    float wA = p[i0], wB = p[i1];
    float dn = wA + wB + 1e-9f;
    wA /= dn; wB /= dn;
    es[t] = i0; es[T_TOKENS + t] = i1;
    wsv[t] = wA; wsv[T_TOKENS + t] = wB;
    atomicAdd(&counts[i0], 1);
    atomicAdd(&counts[i1], 1);
  }
}

// ---------------- padded prefix offsets, zero cursors ----------------
__global__ void offsets_kernel(const int* __restrict__ counts, int* __restrict__ off,
                               int* __restrict__ cursor)
{
  if (threadIdx.x == 0) {
    int o = 0;
    for (int e = 0; e < NEXP; e++) {
      off[e] = o;
      o += ((counts[e] + BM - 1) / BM) * BM;
    }
    off[NEXP] = o;
  }
  if (threadIdx.x < NEXP) cursor[threadIdx.x] = 0;
}

// ---------------- token -> row assignment ----------------
__global__ void assign_kernel(const int* __restrict__ es, const float* __restrict__ wsv,
                              const int* __restrict__ off, int* __restrict__ cursor,
                              int* __restrict__ perm, float* __restrict__ wt)
{
  int t = blockIdx.x * blockDim.x + threadIdx.x;
  if (t >= T_TOKENS) return;
#pragma unroll
  for (int s = 0; s < 2; s++) {
    int e = es[s * T_TOKENS + t];
    int slot = atomicAdd(&cursor[e], 1);
    int r = off[e] + slot;
    perm[r] = t;
    wt[r] = wsv[s * T_TOKENS + t];
  }
}

// ---------------- weight fp32 [E][R][C] -> bf16 transposed [E][C][R] ----------------
__global__ __launch_bounds__(256) void transpose_cvt_kernel(
    const float* __restrict__ src, bf16* __restrict__ dst, int R, int C)
{
  __shared__ bf16 tile[64][66];
  int e = blockIdx.z;
  int r0 = blockIdx.y * 64, c0 = blockIdx.x * 64;
  const float* s = src + (size_t)e * R * C;
  bf16* d = dst + (size_t)e * R * C;
  int tr = threadIdx.x >> 4;
  int tc4 = (threadIdx.x & 15) * 4;
#pragma unroll
  for (int i = 0; i < 4; i++) {
    int r = tr + i * 16;
    float4 v = *(const float4*)(s + (size_t)(r0 + r) * C + c0 + tc4);
    tile[tc4 + 0][r] = (bf16)v.x;
    tile[tc4 + 1][r] = (bf16)v.y;
    tile[tc4 + 2][r] = (bf16)v.z;
    tile[tc4 + 3][r] = (bf16)v.w;
  }
  __syncthreads();
  int cc0 = threadIdx.x >> 3;
  int ch = (threadIdx.x & 7) * 8;
#pragma unroll
  for (int i = 0; i < 2; i++) {
    int cc = cc0 + i * 32;
    const unsigned int* rp = (const unsigned int*)&tile[cc][0];
    unsigned int u0 = rp[ch / 2 + 0];
    unsigned int u1 = rp[ch / 2 + 1];
    unsigned int u2 = rp[ch / 2 + 2];
    unsigned int u3 = rp[ch / 2 + 3];
    uint4 o = { u0, u1, u2, u3 };
    *(uint4*)(d + (size_t)(c0 + cc) * R + r0 + ch) = o;
  }
}

// ---------------- out = bias (broadcast) ----------------
__global__ void out_init_kernel(float* __restrict__ out, const float* __restrict__ bias)
{
  int i = blockIdx.x * blockDim.x + threadIdx.x;
  out[i] = bias[i & (DMODEL - 1)];
}

// ---------------- counted-vmcnt pipelined MFMA GEMM (T1-chunked+T2+T3+T4+T5) ----
// 512 thr = 8 waves (2M x 4N); per-wave out 128 x (FN*16). BN = FN*64.
// XCD-CHUNKED tile mapping: X = bid&7 (dispatch round-robin = XCD),
//   j = bid>>3, nt = j&7, mt = (j>>3)*8 + X  ->  mt === X (mod 8).
// Per-XCD concurrent working set per K-step = 4-5 A-panels + 8 B-slices
// (~400 KB << 4 MB L2): every staged byte fetched once into XCD L2,
// reused 4-8x. (Round-4 nt-pinning put a 4 MB B slab in L2 and the A
// stream evicted it -> ~50% L3/HBM traffic -> latency-bound at 2 TB/s.)
// 4 phases/K-tile, counted vmcnt gates (never 0 in loop), group-major LDS
// remap, XOR swizzle byte^=(s&7)<<4 with pre-swizzled global source.
template<int KDIM, int NDIM, int FN, bool GELU_STORE>
__global__ __launch_bounds__(512, 2) void moe_gemm256_kernel(
    const bf16* __restrict__ A, const bf16* __restrict__ W,
    bf16* __restrict__ hidden, float* __restrict__ out,
    const int* __restrict__ perm, const float* __restrict__ wt,
    const int* __restrict__ off)
{
  constexpr int BN_ = FN * 64;
  constexpr int NQ  = FN / 2;
  constexpr int NT  = KDIM / BK;
  constexpr int BLOADS = FN;

  int X  = blockIdx.x & 7;        // XCD (round-robin dispatch)
  int j  = blockIdx.x >> 3;
  int nt = j & 7;
  int mt = (j >> 3) * 8 + X;      // mt === X (mod 8): A-panel XCD-exclusive
  int row0 = mt * BM;
  int total = off[NEXP];
  if (row0 >= total) return;
  int e = 0;
  while (row0 >= off[e + 1]) e++;
  int n0 = nt * BN_;
  const bf16* Wb = W + (size_t)e * NDIM * KDIM;

  __shared__ bf16 As[2][256 * 64];
  __shared__ bf16 Bs[2][BN_ * 64];

  int tid  = threadIdx.x;
  int lane = tid & 63;
  int wid  = tid >> 6;
  int wm   = wid >> 2;
  int wn   = wid & 3;
  int l15  = lane & 15;
  int hi16 = (lane >> 4) << 4;
  int srow = tid >> 3;                          // 0..63
  int scol = ((tid & 7) ^ (srow & 7)) * 8;      // pre-swizzled source col (elems)

  unsigned aoff[4];
#pragma unroll
  for (int i = 0; i < 4; ++i) {
    int s = i * 64 + srow;
    int g = ((s >> 6) & 1) * 128 + (s >> 7) * 64 + (s & 63);
    unsigned rowid;
    if (GELU_STORE) { int p = perm[row0 + g]; rowid = (p < 0) ? 0u : (unsigned)p; }
    else            { rowid = (unsigned)(row0 + g); }
    aoff[i] = rowid * (unsigned)KDIM;
  }
  unsigned boff[BLOADS];
#pragma unroll
  for (int i = 0; i < BLOADS; ++i) {
    int s = i * 64 + srow;
    int g;
    if constexpr (FN == 4) g = ((s >> 5) & 3) * 64 + (s >> 7) * 32 + (s & 31);
    else                   g = ((s >> 4) & 3) * 32 + (s >> 6) * 16 + (s & 15);
    boff[i] = (unsigned)(n0 + g) * (unsigned)KDIM;
  }

  f32x4 acc[8][FN];
#pragma unroll
  for (int am = 0; am < 8; ++am)
#pragma unroll
    for (int an = 0; an < FN; ++an)
      acc[am][an] = (f32x4){0.f, 0.f, 0.f, 0.f};

#define STAGE_A(bb, t, grp) do {                                             \
    int k0_ = (t) * BK;                                                      \
    _Pragma("unroll")                                                        \
    for (int i = 2 * (grp); i < 2 * (grp) + 2; ++i)                          \
      gload_lds16(A + aoff[i] + k0_ + scol, &As[bb][(unsigned)(i * 512 + tid) * 8]); \
  } while (0)

#define STAGE_B(bb, t, grp) do {                                             \
    int k0_ = (t) * BK;                                                      \
    _Pragma("unroll")                                                        \
    for (int i = (BLOADS / 2) * (grp); i < (BLOADS / 2) * ((grp) + 1); ++i)  \
      gload_lds16(Wb + boff[i] + k0_ + scol, &Bs[bb][(unsigned)(i * 512 + tid) * 8]); \
  } while (0)

  bf16x8 af[4][2];
  bf16x8 bfr[2][NQ][2];

#define READ_A(bb, qm) do {                                                  \
    const char* base_ = (const char*)&As[bb][0];                             \
    _Pragma("unroll")                                                        \
    for (int m = 0; m < 4; ++m)                                              \
      _Pragma("unroll")                                                      \
      for (int kk = 0; kk < 2; ++kk) {                                       \
        int s_  = (qm) * 128 + wm * 64 + m * 16 + l15;                       \
        int cb_ = (kk * 64 + hi16) ^ ((s_ & 7) << 4);                        \
        af[m][kk] = *(const bf16x8*)(base_ + s_ * 128 + cb_);                \
      }                                                                      \
  } while (0)

#define READ_B(bb, qn) do {                                                  \
    const char* base_ = (const char*)&Bs[bb][0];                             \
    _Pragma("unroll")                                                        \
    for (int n = 0; n < NQ; ++n)                                             \
      _Pragma("unroll")                                                      \
      for (int kk = 0; kk < 2; ++kk) {                                       \
        int s_  = (qn) * (BN_ / 2) + wn * (BN_ / 8) + n * 16 + l15;          \
        int cb_ = (kk * 64 + hi16) ^ ((s_ & 7) << 4);                        \
        bfr[qn][n][kk] = *(const bf16x8*)(base_ + s_ * 128 + cb_);           \
      }                                                                      \
  } while (0)

#define DO_MFMA(qm, qn) do {                                                 \
    __builtin_amdgcn_s_setprio(1);                                           \
    _Pragma("unroll")                                                        \
    for (int m = 0; m < 4; ++m)                                              \
      _Pragma("unroll")                                                      \
      for (int n = 0; n < NQ; ++n)                                           \
        _Pragma("unroll")                                                    \
        for (int kk = 0; kk < 2; ++kk)                                       \
          acc[(qm) * 4 + m][(qn) * NQ + n] = __builtin_amdgcn_mfma_f32_16x16x32_bf16( \
              af[m][kk], bfr[qn][n][kk], acc[(qm) * 4 + m][(qn) * NQ + n], 0, 0, 0); \
    __builtin_amdgcn_s_setprio(0);                                           \
    __builtin_amdgcn_sched_barrier(0);                                       \
  } while (0)

#define GATE_A  do { if constexpr (FN == 4) asm volatile("s_waitcnt vmcnt(6)" ::: "memory"); \
                     else                   asm volatile("s_waitcnt vmcnt(5)" ::: "memory"); } while (0)
#define GATE_C  do { if constexpr (FN == 4) asm volatile("s_waitcnt vmcnt(6)" ::: "memory"); \
                     else                   asm volatile("s_waitcnt vmcnt(4)" ::: "memory"); } while (0)
#define LGKM_SB do { asm volatile("s_waitcnt lgkmcnt(0)" ::: "memory");      \
                     __builtin_amdgcn_sched_barrier(0); } while (0)

  // prologue: full tile 0, drain once
  STAGE_A(0, 0, 0); STAGE_B(0, 0, 0); STAGE_B(0, 0, 1); STAGE_A(0, 0, 1);
  asm volatile("s_waitcnt vmcnt(0)" ::: "memory");
  __builtin_amdgcn_s_barrier();

  for (int t = 0; t < NT; ++t) {
    int b = t & 1;
    bool pf = (t + 1 < NT);
    // ---- phase 0: (qm0,qn0); stage A-g0(t+1)
    if (pf) STAGE_A(b ^ 1, t + 1, 0);
    GATE_A;
    __builtin_amdgcn_s_barrier();
    READ_A(b, 0); READ_B(b, 0);
    LGKM_SB;
    DO_MFMA(0, 0);
    // ---- phase 1: (qm0,qn1); stage B-g0(t+1)
    if (pf) STAGE_B(b ^ 1, t + 1, 0);
    GATE_A;
    __builtin_amdgcn_s_barrier();
    READ_B(b, 1);
    LGKM_SB;
    DO_MFMA(0, 1);
    // ---- phase 2: (qm1,qn0); stage B-g1(t+1)
    if (pf) STAGE_B(b ^ 1, t + 1, 1);
    GATE_C;
    __builtin_amdgcn_s_barrier();
    READ_A(b, 1);
    LGKM_SB;
    DO_MFMA(1, 0);
    // ---- phase 3: (qm1,qn1); stage A-g1(t+1); no gate needed
    if (pf) STAGE_A(b ^ 1, t + 1, 1);
    __builtin_amdgcn_s_barrier();
    DO_MFMA(1, 1);
  }

#undef STAGE_A
#undef STAGE_B
#undef READ_A
#undef READ_B
#undef DO_MFMA
#undef GATE_A
#undef GATE_C
#undef LGKM_SB

  // epilogue: C/D layout col = lane&15, row = (lane>>4)*4 + j
#pragma unroll
  for (int am = 0; am < 8; ++am) {
    int rb = row0 + wm * 128 + am * 16 + ((lane >> 4) << 2);
#pragma unroll
    for (int j2 = 0; j2 < 4; ++j2) {
      int rg = rb + j2;
      if (GELU_STORE) {
#pragma unroll
        for (int an = 0; an < FN; ++an) {
          float v  = acc[am][an][j2];
          float gv = 0.5f * v * (1.0f + erff(v * 0.70710678118654752f));
          hidden[(unsigned)rg * NDIM + (n0 + wn * (FN * 16) + an * 16 + l15)] = (bf16)gv;
        }
      } else {
        int p = perm[rg];
        if (p >= 0) {
          float w = wt[rg];
#pragma unroll
          for (int an = 0; an < FN; ++an)
            atomicAdd(&out[(unsigned)p * DMODEL + (n0 + wn * (FN * 16) + an * 16 + l15)],
                      w * acc[am][an][j2]);
        }
      }
    }
  }
}

// ---------------- host ----------------
extern "C" void kernel_launch(void* const* d_in, const int* in_sizes, int n_in,
                              void* d_out, int out_size, void* d_ws, size_t ws_size,
                              hipStream_t stream)
{
  const float* x    = (const float*)d_in[0];
  const float* gw   = (const float*)d_in[1];
  const float* w1   = (const float*)d_in[2];
  const float* w2   = (const float*)d_in[3];
  const float* bias = (const float*)d_in[4];
  float* out = (float*)d_out;

  char* ws = (char*)d_ws;
  size_t o = 0;
  auto alloc = [&](size_t bytes) {
    void* p = ws + o;
    o = (o + bytes + 255) & ~(size_t)255;
    return p;
  };
  bf16*  xb     = (bf16*) alloc((size_t)T_TOKENS * DMODEL * 2);
  bf16*  w1t    = (bf16*) alloc((size_t)NEXP * HDIM * DMODEL * 2);   // [E][H][D]
  bf16*  w2t    = (bf16*) alloc((size_t)NEXP * DMODEL * HDIM * 2);   // [E][D][H]
  bf16*  hidden = (bf16*) alloc((size_t)MAXROWS * HDIM * 2);
  int*   perm   = (int*)  alloc((size_t)MAXROWS * 4);
  float* wt     = (float*)alloc((size_t)MAXROWS * 4);
  int*   es     = (int*)  alloc((size_t)2 * T_TOKENS * 4);
  float* wsv    = (float*)alloc((size_t)2 * T_TOKENS * 4);
  int*   counts = (int*)  alloc(64);
  int*   offs   = (int*)  alloc(64);
  int*   cursor = (int*)  alloc(64);

  hipMemsetAsync(counts, 0, 64, stream);
  hipMemsetAsync(perm, 0xFF, (size_t)MAXROWS * 4, stream);

  router_kernel<<<T_TOKENS / 4, 256, 0, stream>>>(x, gw, xb, es, wsv, counts);
  offsets_kernel<<<1, 64, 0, stream>>>(counts, offs, cursor);
  assign_kernel<<<T_TOKENS / 256, 256, 0, stream>>>(es, wsv, offs, cursor, perm, wt);

  // w1 [E][D][H] -> w1t [E][H][D]
  transpose_cvt_kernel<<<dim3(HDIM / 64, DMODEL / 64, NEXP), 256, 0, stream>>>(w1, w1t, DMODEL, HDIM);
  // w2 [E][H][D] -> w2t [E][D][H]
  transpose_cvt_kernel<<<dim3(DMODEL / 64, HDIM / 64, NEXP), 256, 0, stream>>>(w2, w2t, HDIM, DMODEL);

  out_init_kernel<<<(T_TOKENS * DMODEL) / 256, 256, 0, stream>>>(out, bias);

  // G1: [rows,1024] x w1t[e][2048,1024]^T -> gelu -> hidden ; BN=256 (FN=4)
  moe_gemm256_kernel<DMODEL, HDIM, 4, true><<<MTILES * 8, 512, 0, stream>>>(
      xb, w1t, hidden, nullptr, perm, wt, offs);
  // G2: hidden[rows,2048] x w2t[e][1024,2048]^T -> atomic scatter ; BN=128 (FN=2)
  moe_gemm256_kernel<HDIM, DMODEL, 2, false><<<MTILES * 8, 512, 0, stream>>>(
      hidden, w2t, nullptr, out, perm, wt, offs);
}

// Round 6
// 349.469 us; speedup vs baseline: 1.2482x; 1.2482x over previous
//
#include <hip/hip_runtime.h>
#include <hip/hip_bf16.h>
#include <cmath>

// ---------------- problem constants ----------------
#define T_TOKENS 4096   // 2*2048
#define DMODEL   1024
#define HDIM     2048
#define NEXP     8
#define BM 128
#define BN 128
#define BK 64
#define MAXROWS 9216    // 8192 routed rows + worst-case per-expert padding to 128
#define MTILES  (MAXROWS / BM)   // 72

typedef __bf16 bf16;
typedef __bf16 bf16x8 __attribute__((ext_vector_type(8)));
typedef __bf16 bf16x4 __attribute__((ext_vector_type(4)));
typedef float  f32x4  __attribute__((ext_vector_type(4)));

__device__ inline void gload_lds16(const void* g, void* l) {
  __builtin_amdgcn_global_load_lds(
      (const __attribute__((address_space(1))) void*)g,
      (__attribute__((address_space(3))) void*)l, 16, 0, 0);
}

// ---------------- router: logits -> softmax -> top2; also x -> bf16 ----------------
__global__ __launch_bounds__(256) void router_kernel(
    const float* __restrict__ x, const float* __restrict__ gw,
    bf16* __restrict__ xb, int* __restrict__ es, float* __restrict__ wsv,
    int* __restrict__ counts)
{
  int wid = threadIdx.x >> 6, lane = threadIdx.x & 63;
  int t = blockIdx.x * 4 + wid;
  if (t >= T_TOKENS) return;
  const float* xrow = x + (size_t)t * DMODEL;

  double acc[NEXP];
#pragma unroll
  for (int e = 0; e < NEXP; e++) acc[e] = 0.0;

#pragma unroll
  for (int i = 0; i < 4; i++) {
    int d0 = (i * 64 + lane) * 4;
    float4 xv = *(const float4*)(xrow + d0);
    bf16x4 o = { (bf16)xv.x, (bf16)xv.y, (bf16)xv.z, (bf16)xv.w };
    *(bf16x4*)(xb + (size_t)t * DMODEL + d0) = o;
    const float* g0 = gw + (size_t)d0 * NEXP;
    float xs[4] = { xv.x, xv.y, xv.z, xv.w };
#pragma unroll
    for (int j = 0; j < 4; j++)
#pragma unroll
      for (int e = 0; e < NEXP; e++)
        acc[e] += (double)xs[j] * (double)g0[j * NEXP + e];
  }
#pragma unroll
  for (int e = 0; e < NEXP; e++) {
    double v = acc[e];
#pragma unroll
    for (int m = 32; m >= 1; m >>= 1) v += __shfl_xor(v, m, 64);
    acc[e] = v;
  }
  if (lane == 0) {
    float l[NEXP], p[NEXP];
    float mx = -1e30f;
#pragma unroll
    for (int e = 0; e < NEXP; e++) { l[e] = (float)acc[e]; mx = fmaxf(mx, l[e]); }
    float s = 0.f;
#pragma unroll
    for (int e = 0; e < NEXP; e++) { p[e] = __expf(l[e] - mx); s += p[e]; }
#pragma unroll
    for (int e = 0; e < NEXP; e++) p[e] /= s;
    int i0 = 0;
#pragma unroll
    for (int e = 1; e < NEXP; e++) if (p[e] > p[i0]) i0 = e;
    int i1 = (i0 == 0) ? 1 : 0;
#pragma unroll
    for (int e = 0; e < NEXP; e++) if (e != i0 && p[e] > p[i1]) i1 = e;
    float wA = p[i0], wB = p[i1];
    float dn = wA + wB + 1e-9f;
    wA /= dn; wB /= dn;
    es[t] = i0; es[T_TOKENS + t] = i1;
    wsv[t] = wA; wsv[T_TOKENS + t] = wB;
    atomicAdd(&counts[i0], 1);
    atomicAdd(&counts[i1], 1);
  }
}

// ---------------- offsets (pad to BM), zero cursors, init perm = -1 ----------------
__global__ __launch_bounds__(256) void offsets_kernel(
    const int* __restrict__ counts, int* __restrict__ off,
    int* __restrict__ cursor, int* __restrict__ perm)
{
  if (threadIdx.x == 0) {
    int o = 0;
    for (int e = 0; e < NEXP; e++) {
      off[e] = o;
      o += ((counts[e] + BM - 1) / BM) * BM;
    }
    off[NEXP] = o;
  }
  if (threadIdx.x < NEXP) cursor[threadIdx.x] = 0;
  for (int i = threadIdx.x; i < MAXROWS; i += 256) perm[i] = -1;
}

// ---------------- token -> row assignment (+ inverse map for combine) ----------------
__global__ void assign_kernel(const int* __restrict__ es,
                              const int* __restrict__ off, int* __restrict__ cursor,
                              int* __restrict__ perm, int* __restrict__ t2r)
{
  int t = blockIdx.x * blockDim.x + threadIdx.x;
  if (t >= T_TOKENS) return;
#pragma unroll
  for (int s = 0; s < 2; s++) {
    int e = es[s * T_TOKENS + t];
    int slot = atomicAdd(&cursor[e], 1);
    int r = off[e] + slot;
    perm[r] = t;
    t2r[s * T_TOKENS + t] = r;
  }
}

// ---------------- weight fp32 [E][R][C] -> bf16 transposed [E][C][R] ----------------
__global__ __launch_bounds__(256) void transpose_cvt_kernel(
    const float* __restrict__ src, bf16* __restrict__ dst, int R, int C)
{
  __shared__ bf16 tile[64][66];
  int e = blockIdx.z;
  int r0 = blockIdx.y * 64, c0 = blockIdx.x * 64;
  const float* s = src + (size_t)e * R * C;
  bf16* d = dst + (size_t)e * R * C;
  int tr = threadIdx.x >> 4;
  int tc4 = (threadIdx.x & 15) * 4;
#pragma unroll
  for (int i = 0; i < 4; i++) {
    int r = tr + i * 16;
    float4 v = *(const float4*)(s + (size_t)(r0 + r) * C + c0 + tc4);
    tile[tc4 + 0][r] = (bf16)v.x;
    tile[tc4 + 1][r] = (bf16)v.y;
    tile[tc4 + 2][r] = (bf16)v.z;
    tile[tc4 + 3][r] = (bf16)v.w;
  }
  __syncthreads();
  int cc0 = threadIdx.x >> 3;
  int ch = (threadIdx.x & 7) * 8;
#pragma unroll
  for (int i = 0; i < 2; i++) {
    int cc = cc0 + i * 32;
    const unsigned int* rp = (const unsigned int*)&tile[cc][0];
    unsigned int u0 = rp[ch / 2 + 0];
    unsigned int u1 = rp[ch / 2 + 1];
    unsigned int u2 = rp[ch / 2 + 2];
    unsigned int u3 = rp[ch / 2 + 3];
    uint4 o = { u0, u1, u2, u3 };
    *(uint4*)(d + (size_t)(c0 + cc) * R + r0 + ch) = o;
  }
}

// ---------------- MFMA GEMM, R1 high-occupancy structure + T2 swizzle + XCD chunk ----
// 128x128x64 tile, 4 waves (2x2), single 32KB LDS buffer -> ~5 blocks/CU.
// Occupancy is the proven lever (R1 5/CU:122us < R2 2/CU:140 < R3-5 1/CU:151).
// XOR swizzle byte^=(row&7)<<4 on LDS reads, inverse-swizzled global source col
// (rule #21); conflicts were 1.3e7 cyc in R1 -> ~0.
// XCD-chunked mapping (R5: FETCH -45%): X=bid&7, j=bid>>3, nt=j%NTN,
// mt=(j/NTN)*8+X  (MTILES=72=9*8 exact).
// G1 (GELU): A rows gathered via perm from xb. G2: A = hidden rows direct,
// plain bf16 store to y (no atomics; combine kernel applies weights+bias).
template<int KDIM, int NDIM, bool GELU>
__global__ __launch_bounds__(256) void moe_gemm_kernel(
    const bf16* __restrict__ A, const bf16* __restrict__ W,
    bf16* __restrict__ dst, const int* __restrict__ perm,
    const int* __restrict__ off)
{
  constexpr int NTN = NDIM / BN;
  int X  = blockIdx.x & 7;
  int j  = blockIdx.x >> 3;
  int nt = j % NTN;
  int mt = (j / NTN) * 8 + X;
  int row0 = mt * BM;
  int total = off[NEXP];
  if (row0 >= total) return;
  int e = 0;
  while (row0 >= off[e + 1]) e++;
  int n0 = nt * BN;
  const bf16* Wb = W + (size_t)e * NDIM * KDIM;

  __shared__ bf16 As[BM * BK];
  __shared__ bf16 Bs[BN * BK];

  int tid = threadIdx.x;
  int lane = tid & 63;
  int wid = tid >> 6;
  int wm = wid >> 1, wn = wid & 1;
  int l15 = lane & 15;
  int hi16 = (lane >> 4) << 4;

  int sr = tid >> 3;                       // staging row 0..31 (+32i)
  int sc8 = tid & 7;                       // LDS 16B slot
  int scol = (sc8 ^ (sr & 7)) * 8;         // inverse-swizzled global col (elems)

  unsigned arow[4];
#pragma unroll
  for (int i = 0; i < 4; i++) {
    int r = sr + i * 32;
    unsigned g;
    if (GELU) { int p = perm[row0 + r]; g = (p < 0) ? 0u : (unsigned)p; }
    else      { g = (unsigned)(row0 + r); }
    arow[i] = g * (unsigned)KDIM;
  }
  unsigned brow[4];
#pragma unroll
  for (int i = 0; i < 4; i++) brow[i] = (unsigned)(n0 + sr + i * 32) * KDIM;

  f32x4 acc[4][4];
#pragma unroll
  for (int m = 0; m < 4; m++)
#pragma unroll
    for (int n = 0; n < 4; n++) acc[m][n] = (f32x4){0.f, 0.f, 0.f, 0.f};

  for (int k0 = 0; k0 < KDIM; k0 += BK) {
#pragma unroll
    for (int i = 0; i < 4; i++)
      gload_lds16(A + arow[i] + k0 + scol, &As[((sr + i * 32) * BK) + sc8 * 8]);
#pragma unroll
    for (int i = 0; i < 4; i++)
      gload_lds16(Wb + brow[i] + k0 + scol, &Bs[((sr + i * 32) * BK) + sc8 * 8]);
    asm volatile("s_waitcnt vmcnt(0)" ::: "memory");
    __syncthreads();

    const char* asB = (const char*)As;
    const char* bsB = (const char*)Bs;
#pragma unroll
    for (int kk = 0; kk < 2; kk++) {
      int kb = kk * 64 + hi16;             // byte col within 128B row
      bf16x8 af[4], bfr[4];
#pragma unroll
      for (int m = 0; m < 4; m++) {
        int r = wm * 64 + m * 16 + l15;
        af[m] = *(const bf16x8*)(asB + r * 128 + (kb ^ ((r & 7) << 4)));
      }
#pragma unroll
      for (int n = 0; n < 4; n++) {
        int r = wn * 64 + n * 16 + l15;
        bfr[n] = *(const bf16x8*)(bsB + r * 128 + (kb ^ ((r & 7) << 4)));
      }
#pragma unroll
      for (int m = 0; m < 4; m++)
#pragma unroll
        for (int n = 0; n < 4; n++)
          acc[m][n] = __builtin_amdgcn_mfma_f32_16x16x32_bf16(af[m], bfr[n], acc[m][n], 0, 0, 0);
    }
    __syncthreads();
  }

  // epilogue: C/D layout col = lane&15, row = (lane>>4)*4 + j2 ; bf16 store
#pragma unroll
  for (int m = 0; m < 4; m++) {
    int rbase = row0 + wm * 64 + m * 16 + ((lane >> 4) << 2);
#pragma unroll
    for (int j2 = 0; j2 < 4; j2++) {
      unsigned rg = (unsigned)(rbase + j2);
#pragma unroll
      for (int n = 0; n < 4; n++) {
        float v = acc[m][n][j2];
        if (GELU) v = 0.5f * v * (1.0f + erff(v * 0.70710678118654752f));
        dst[(size_t)rg * NDIM + (n0 + wn * 64 + n * 16 + l15)] = (bf16)v;
      }
    }
  }
}

// ---------------- combine: out = bias + w0*y[r0] + w1*y[r1] ----------------
__global__ __launch_bounds__(256) void combine_kernel(
    const bf16* __restrict__ y, const int* __restrict__ t2r,
    const float* __restrict__ wsv, const float* __restrict__ bias,
    float* __restrict__ out)
{
  int t = blockIdx.x;
  int d = threadIdx.x * 4;
  int r0 = t2r[t], r1 = t2r[T_TOKENS + t];
  float w0 = wsv[t], w1 = wsv[T_TOKENS + t];
  bf16x4 a = *(const bf16x4*)(y + (size_t)r0 * DMODEL + d);
  bf16x4 b = *(const bf16x4*)(y + (size_t)r1 * DMODEL + d);
  float4 bs = *(const float4*)(bias + d);
  float4 o;
  o.x = bs.x + w0 * (float)a[0] + w1 * (float)b[0];
  o.y = bs.y + w0 * (float)a[1] + w1 * (float)b[1];
  o.z = bs.z + w0 * (float)a[2] + w1 * (float)b[2];
  o.w = bs.w + w0 * (float)a[3] + w1 * (float)b[3];
  *(float4*)(out + (size_t)t * DMODEL + d) = o;
}

// ---------------- host ----------------
extern "C" void kernel_launch(void* const* d_in, const int* in_sizes, int n_in,
                              void* d_out, int out_size, void* d_ws, size_t ws_size,
                              hipStream_t stream)
{
  const float* x    = (const float*)d_in[0];
  const float* gw   = (const float*)d_in[1];
  const float* w1   = (const float*)d_in[2];
  const float* w2   = (const float*)d_in[3];
  const float* bias = (const float*)d_in[4];
  float* out = (float*)d_out;

  char* ws = (char*)d_ws;
  size_t o = 0;
  auto alloc = [&](size_t bytes) {
    void* p = ws + o;
    o = (o + bytes + 255) & ~(size_t)255;
    return p;
  };
  bf16*  xb     = (bf16*) alloc((size_t)T_TOKENS * DMODEL * 2);       // 8 MB
  bf16*  w1t    = (bf16*) alloc((size_t)NEXP * HDIM * DMODEL * 2);    // 32 MB [E][H][D]
  bf16*  w2t    = (bf16*) alloc((size_t)NEXP * DMODEL * HDIM * 2);    // 32 MB [E][D][H]
  bf16*  hidden = (bf16*) alloc((size_t)MAXROWS * HDIM * 2);          // 37.7 MB
  int*   perm   = (int*)  alloc((size_t)MAXROWS * 4);
  int*   t2r    = (int*)  alloc((size_t)2 * T_TOKENS * 4);
  int*   es     = (int*)  alloc((size_t)2 * T_TOKENS * 4);
  float* wsv    = (float*)alloc((size_t)2 * T_TOKENS * 4);
  int*   counts = (int*)  alloc(64);
  int*   offs   = (int*)  alloc(64);
  int*   cursor = (int*)  alloc(64);
  // y aliases w1t: w1t is dead after G1; G2 writes y before combine reads it.
  bf16*  y      = w1t;   // MAXROWS*DMODEL*2 = 18.9 MB <= 32 MB

  hipMemsetAsync(counts, 0, 64, stream);

  router_kernel<<<T_TOKENS / 4, 256, 0, stream>>>(x, gw, xb, es, wsv, counts);
  offsets_kernel<<<1, 256, 0, stream>>>(counts, offs, cursor, perm);
  assign_kernel<<<T_TOKENS / 256, 256, 0, stream>>>(es, offs, cursor, perm, t2r);

  // w1 [E][D][H] -> w1t [E][H][D]
  transpose_cvt_kernel<<<dim3(HDIM / 64, DMODEL / 64, NEXP), 256, 0, stream>>>(w1, w1t, DMODEL, HDIM);
  // w2 [E][H][D] -> w2t [E][D][H]
  transpose_cvt_kernel<<<dim3(DMODEL / 64, HDIM / 64, NEXP), 256, 0, stream>>>(w2, w2t, HDIM, DMODEL);

  // G1: xb(perm rows) x w1t^T -> gelu -> hidden   [grid 72*16*8/8... 72/8*16*8 = 1152]
  moe_gemm_kernel<DMODEL, HDIM, true><<<MTILES * (HDIM / BN), 256, 0, stream>>>(
      xb, w1t, hidden, perm, offs);
  // G2: hidden x w2t^T -> y (plain bf16 rows)     [grid 72*8 = 576]
  moe_gemm_kernel<HDIM, DMODEL, false><<<MTILES * (DMODEL / BN), 256, 0, stream>>>(
      hidden, w2t, y, perm, offs);

  combine_kernel<<<T_TOKENS, 256, 0, stream>>>(y, t2r, wsv, bias, out);
}

// Round 7
// 237.555 us; speedup vs baseline: 1.8362x; 1.4711x over previous
//
#include <hip/hip_runtime.h>
#include <hip/hip_bf16.h>
#include <cmath>

// ---------------- problem constants ----------------
#define T_TOKENS 4096   // 2*2048
#define DMODEL   1024
#define HDIM     2048
#define NEXP     8
#define BM 128
#define BN 128
#define BK 64
#define MAXROWS 9216    // 8192 routed rows + worst-case per-expert padding to 128
#define MTILES  (MAXROWS / BM)   // 72

typedef __bf16 bf16;
typedef __bf16 bf16x8 __attribute__((ext_vector_type(8)));
typedef __bf16 bf16x4 __attribute__((ext_vector_type(4)));
typedef float  f32x4  __attribute__((ext_vector_type(4)));

__device__ inline void gload_lds16(const void* g, void* l) {
  __builtin_amdgcn_global_load_lds(
      (const __attribute__((address_space(1))) void*)g,
      (__attribute__((address_space(3))) void*)l, 16, 0, 0);
}

// ---------------- router: logits -> softmax -> top2; also x -> bf16 ----------------
// NO atomics (round-6 PMC: 8192 same-line atomicAdds serialized ~30cyc each
// = ~100us, the entire kernel duration; counts now come from setup_kernel).
__global__ __launch_bounds__(256) void router_kernel(
    const float* __restrict__ x, const float* __restrict__ gw,
    bf16* __restrict__ xb, int* __restrict__ es, float* __restrict__ wsv)
{
  int wid = threadIdx.x >> 6, lane = threadIdx.x & 63;
  int t = blockIdx.x * 4 + wid;
  if (t >= T_TOKENS) return;
  const float* xrow = x + (size_t)t * DMODEL;

  double acc[NEXP];
#pragma unroll
  for (int e = 0; e < NEXP; e++) acc[e] = 0.0;

#pragma unroll
  for (int i = 0; i < 4; i++) {
    int d0 = (i * 64 + lane) * 4;
    float4 xv = *(const float4*)(xrow + d0);
    bf16x4 o = { (bf16)xv.x, (bf16)xv.y, (bf16)xv.z, (bf16)xv.w };
    *(bf16x4*)(xb + (size_t)t * DMODEL + d0) = o;
    const float* g0 = gw + (size_t)d0 * NEXP;
    float xs[4] = { xv.x, xv.y, xv.z, xv.w };
#pragma unroll
    for (int j = 0; j < 4; j++)
#pragma unroll
      for (int e = 0; e < NEXP; e++)
        acc[e] += (double)xs[j] * (double)g0[j * NEXP + e];
  }
#pragma unroll
  for (int e = 0; e < NEXP; e++) {
    double v = acc[e];
#pragma unroll
    for (int m = 32; m >= 1; m >>= 1) v += __shfl_xor(v, m, 64);
    acc[e] = v;
  }
  if (lane == 0) {
    float l[NEXP], p[NEXP];
    float mx = -1e30f;
#pragma unroll
    for (int e = 0; e < NEXP; e++) { l[e] = (float)acc[e]; mx = fmaxf(mx, l[e]); }
    float s = 0.f;
#pragma unroll
    for (int e = 0; e < NEXP; e++) { p[e] = __expf(l[e] - mx); s += p[e]; }
#pragma unroll
    for (int e = 0; e < NEXP; e++) p[e] /= s;
    int i0 = 0;
#pragma unroll
    for (int e = 1; e < NEXP; e++) if (p[e] > p[i0]) i0 = e;
    int i1 = (i0 == 0) ? 1 : 0;
#pragma unroll
    for (int e = 0; e < NEXP; e++) if (e != i0 && p[e] > p[i1]) i1 = e;
    float wA = p[i0], wB = p[i1];
    float dn = wA + wB + 1e-9f;
    wA /= dn; wB /= dn;
    es[t] = i0; es[T_TOKENS + t] = i1;
    wsv[t] = wA; wsv[T_TOKENS + t] = wB;
  }
}

// ---------------- setup: histogram + offsets + deterministic assignment ----------
// Single block, 256 threads, zero global atomics. Each thread owns 32 entries
// of es[2*T]; register histogram (static-indexed), LDS 256x8 exclusive prefix,
// padded per-expert offsets, then rank-ordered perm/t2r writes.
__global__ __launch_bounds__(256) void setup_kernel(
    const int* __restrict__ es, int* __restrict__ off,
    int* __restrict__ perm, int* __restrict__ t2r)
{
  __shared__ int hist[256 * NEXP];
  __shared__ int offL[NEXP + 1];
  int tid = threadIdx.x;

  // init perm = -1 (pad rows)
  for (int i = tid; i < MAXROWS; i += 256) perm[i] = -1;

  // local histogram over entries [tid*32, tid*32+32)
  int h[NEXP];
#pragma unroll
  for (int e = 0; e < NEXP; e++) h[e] = 0;
  int base = tid * 32;
#pragma unroll
  for (int k = 0; k < 32; k++) {
    int ev = es[base + k];
#pragma unroll
    for (int e = 0; e < NEXP; e++) h[e] += (ev == e);
  }
#pragma unroll
  for (int e = 0; e < NEXP; e++) hist[tid * NEXP + e] = h[e];
  __syncthreads();

  // exclusive prefix per expert (8 threads scan 256 entries in parallel)
  if (tid < NEXP) {
    int s = 0;
    for (int t = 0; t < 256; t++) {
      int v = hist[t * NEXP + tid];
      hist[t * NEXP + tid] = s;
      s += v;
    }
    offL[tid] = s;   // total count for expert tid (temporarily)
  }
  __syncthreads();
  if (tid == 0) {
    int o = 0;
    int tot[NEXP];
#pragma unroll
    for (int e = 0; e < NEXP; e++) tot[e] = offL[e];
#pragma unroll
    for (int e = 0; e < NEXP; e++) {
      offL[e] = o;
      off[e] = o;
      o += ((tot[e] + BM - 1) / BM) * BM;
    }
    offL[NEXP] = o;
    off[NEXP] = o;
  }
  __syncthreads();

  // rank-ordered writes
  int run[NEXP];
#pragma unroll
  for (int e = 0; e < NEXP; e++) run[e] = offL[e] + hist[tid * NEXP + e];
#pragma unroll
  for (int k = 0; k < 32; k++) {
    int i = base + k;
    int ev = es[i];
    int row = 0;
#pragma unroll
    for (int e = 0; e < NEXP; e++) {
      if (ev == e) { row = run[e]; run[e] = row + 1; }
    }
    perm[row] = i & (T_TOKENS - 1);
    t2r[i] = row;
  }
}

// ---------------- weight fp32 [E][R][C] -> bf16 transposed [E][C][R] ----------------
__global__ __launch_bounds__(256) void transpose_cvt_kernel(
    const float* __restrict__ src, bf16* __restrict__ dst, int R, int C)
{
  __shared__ bf16 tile[64][66];
  int e = blockIdx.z;
  int r0 = blockIdx.y * 64, c0 = blockIdx.x * 64;
  const float* s = src + (size_t)e * R * C;
  bf16* d = dst + (size_t)e * R * C;
  int tr = threadIdx.x >> 4;
  int tc4 = (threadIdx.x & 15) * 4;
#pragma unroll
  for (int i = 0; i < 4; i++) {
    int r = tr + i * 16;
    float4 v = *(const float4*)(s + (size_t)(r0 + r) * C + c0 + tc4);
    tile[tc4 + 0][r] = (bf16)v.x;
    tile[tc4 + 1][r] = (bf16)v.y;
    tile[tc4 + 2][r] = (bf16)v.z;
    tile[tc4 + 3][r] = (bf16)v.w;
  }
  __syncthreads();
  int cc0 = threadIdx.x >> 3;
  int ch = (threadIdx.x & 7) * 8;
#pragma unroll
  for (int i = 0; i < 2; i++) {
    int cc = cc0 + i * 32;
    const unsigned int* rp = (const unsigned int*)&tile[cc][0];
    unsigned int u0 = rp[ch / 2 + 0];
    unsigned int u1 = rp[ch / 2 + 1];
    unsigned int u2 = rp[ch / 2 + 2];
    unsigned int u3 = rp[ch / 2 + 3];
    uint4 o = { u0, u1, u2, u3 };
    *(uint4*)(d + (size_t)(c0 + cc) * R + r0 + ch) = o;
  }
}

// ---------------- MFMA GEMM, high-occupancy + T2 swizzle + XCD chunk ----------------
template<int KDIM, int NDIM, bool GELU>
__global__ __launch_bounds__(256) void moe_gemm_kernel(
    const bf16* __restrict__ A, const bf16* __restrict__ W,
    bf16* __restrict__ dst, const int* __restrict__ perm,
    const int* __restrict__ off)
{
  constexpr int NTN = NDIM / BN;
  int X  = blockIdx.x & 7;
  int j  = blockIdx.x >> 3;
  int nt = j % NTN;
  int mt = (j / NTN) * 8 + X;
  int row0 = mt * BM;
  int total = off[NEXP];
  if (row0 >= total) return;
  int e = 0;
  while (row0 >= off[e + 1]) e++;
  int n0 = nt * BN;
  const bf16* Wb = W + (size_t)e * NDIM * KDIM;

  __shared__ bf16 As[BM * BK];
  __shared__ bf16 Bs[BN * BK];

  int tid = threadIdx.x;
  int lane = tid & 63;
  int wid = tid >> 6;
  int wm = wid >> 1, wn = wid & 1;
  int l15 = lane & 15;
  int hi16 = (lane >> 4) << 4;

  int sr = tid >> 3;                       // staging row 0..31 (+32i)
  int sc8 = tid & 7;                       // LDS 16B slot
  int scol = (sc8 ^ (sr & 7)) * 8;         // inverse-swizzled global col (elems)

  unsigned arow[4];
#pragma unroll
  for (int i = 0; i < 4; i++) {
    int r = sr + i * 32;
    unsigned g;
    if (GELU) { int p = perm[row0 + r]; g = (p < 0) ? 0u : (unsigned)p; }
    else      { g = (unsigned)(row0 + r); }
    arow[i] = g * (unsigned)KDIM;
  }
  unsigned brow[4];
#pragma unroll
  for (int i = 0; i < 4; i++) brow[i] = (unsigned)(n0 + sr + i * 32) * KDIM;

  f32x4 acc[4][4];
#pragma unroll
  for (int m = 0; m < 4; m++)
#pragma unroll
    for (int n = 0; n < 4; n++) acc[m][n] = (f32x4){0.f, 0.f, 0.f, 0.f};

  for (int k0 = 0; k0 < KDIM; k0 += BK) {
#pragma unroll
    for (int i = 0; i < 4; i++)
      gload_lds16(A + arow[i] + k0 + scol, &As[((sr + i * 32) * BK) + sc8 * 8]);
#pragma unroll
    for (int i = 0; i < 4; i++)
      gload_lds16(Wb + brow[i] + k0 + scol, &Bs[((sr + i * 32) * BK) + sc8 * 8]);
    asm volatile("s_waitcnt vmcnt(0)" ::: "memory");
    __syncthreads();

    const char* asB = (const char*)As;
    const char* bsB = (const char*)Bs;
#pragma unroll
    for (int kk = 0; kk < 2; kk++) {
      int kb = kk * 64 + hi16;             // byte col within 128B row
      bf16x8 af[4], bfr[4];
#pragma unroll
      for (int m = 0; m < 4; m++) {
        int r = wm * 64 + m * 16 + l15;
        af[m] = *(const bf16x8*)(asB + r * 128 + (kb ^ ((r & 7) << 4)));
      }
#pragma unroll
      for (int n = 0; n < 4; n++) {
        int r = wn * 64 + n * 16 + l15;
        bfr[n] = *(const bf16x8*)(bsB + r * 128 + (kb ^ ((r & 7) << 4)));
      }
#pragma unroll
      for (int m = 0; m < 4; m++)
#pragma unroll
        for (int n = 0; n < 4; n++)
          acc[m][n] = __builtin_amdgcn_mfma_f32_16x16x32_bf16(af[m], bfr[n], acc[m][n], 0, 0, 0);
    }
    __syncthreads();
  }

  // epilogue: C/D layout col = lane&15, row = (lane>>4)*4 + j2 ; bf16 store
#pragma unroll
  for (int m = 0; m < 4; m++) {
    int rbase = row0 + wm * 64 + m * 16 + ((lane >> 4) << 2);
#pragma unroll
    for (int j2 = 0; j2 < 4; j2++) {
      unsigned rg = (unsigned)(rbase + j2);
#pragma unroll
      for (int n = 0; n < 4; n++) {
        float v = acc[m][n][j2];
        if (GELU) v = 0.5f * v * (1.0f + erff(v * 0.70710678118654752f));
        dst[(size_t)rg * NDIM + (n0 + wn * 64 + n * 16 + l15)] = (bf16)v;
      }
    }
  }
}

// ---------------- combine: out = bias + w0*y[r0] + w1*y[r1] ----------------
__global__ __launch_bounds__(256) void combine_kernel(
    const bf16* __restrict__ y, const int* __restrict__ t2r,
    const float* __restrict__ wsv, const float* __restrict__ bias,
    float* __restrict__ out)
{
  int t = blockIdx.x;
  int d = threadIdx.x * 4;
  int r0 = t2r[t], r1 = t2r[T_TOKENS + t];
  float w0 = wsv[t], w1 = wsv[T_TOKENS + t];
  bf16x4 a = *(const bf16x4*)(y + (size_t)r0 * DMODEL + d);
  bf16x4 b = *(const bf16x4*)(y + (size_t)r1 * DMODEL + d);
  float4 bs = *(const float4*)(bias + d);
  float4 o;
  o.x = bs.x + w0 * (float)a[0] + w1 * (float)b[0];
  o.y = bs.y + w0 * (float)a[1] + w1 * (float)b[1];
  o.z = bs.z + w0 * (float)a[2] + w1 * (float)b[2];
  o.w = bs.w + w0 * (float)a[3] + w1 * (float)b[3];
  *(float4*)(out + (size_t)t * DMODEL + d) = o;
}

// ---------------- host ----------------
extern "C" void kernel_launch(void* const* d_in, const int* in_sizes, int n_in,
                              void* d_out, int out_size, void* d_ws, size_t ws_size,
                              hipStream_t stream)
{
  const float* x    = (const float*)d_in[0];
  const float* gw   = (const float*)d_in[1];
  const float* w1   = (const float*)d_in[2];
  const float* w2   = (const float*)d_in[3];
  const float* bias = (const float*)d_in[4];
  float* out = (float*)d_out;

  char* ws = (char*)d_ws;
  size_t o = 0;
  auto alloc = [&](size_t bytes) {
    void* p = ws + o;
    o = (o + bytes + 255) & ~(size_t)255;
    return p;
  };
  bf16*  xb     = (bf16*) alloc((size_t)T_TOKENS * DMODEL * 2);       // 8 MB
  bf16*  w1t    = (bf16*) alloc((size_t)NEXP * HDIM * DMODEL * 2);    // 32 MB [E][H][D]
  bf16*  w2t    = (bf16*) alloc((size_t)NEXP * DMODEL * HDIM * 2);    // 32 MB [E][D][H]
  bf16*  hidden = (bf16*) alloc((size_t)MAXROWS * HDIM * 2);          // 37.7 MB
  int*   perm   = (int*)  alloc((size_t)MAXROWS * 4);
  int*   t2r    = (int*)  alloc((size_t)2 * T_TOKENS * 4);
  int*   es     = (int*)  alloc((size_t)2 * T_TOKENS * 4);
  float* wsv    = (float*)alloc((size_t)2 * T_TOKENS * 4);
  int*   offs   = (int*)  alloc(64);
  // y aliases w1t: w1t is dead after G1; G2 writes y before combine reads it.
  bf16*  y      = w1t;   // MAXROWS*DMODEL*2 = 18.9 MB <= 32 MB

  router_kernel<<<T_TOKENS / 4, 256, 0, stream>>>(x, gw, xb, es, wsv);
  setup_kernel<<<1, 256, 0, stream>>>(es, offs, perm, t2r);

  // w1 [E][D][H] -> w1t [E][H][D]
  transpose_cvt_kernel<<<dim3(HDIM / 64, DMODEL / 64, NEXP), 256, 0, stream>>>(w1, w1t, DMODEL, HDIM);
  // w2 [E][H][D] -> w2t [E][D][H]
  transpose_cvt_kernel<<<dim3(DMODEL / 64, HDIM / 64, NEXP), 256, 0, stream>>>(w2, w2t, HDIM, DMODEL);

  // G1: xb(perm rows) x w1t^T -> gelu -> hidden
  moe_gemm_kernel<DMODEL, HDIM, true><<<MTILES * (HDIM / BN), 256, 0, stream>>>(
      xb, w1t, hidden, perm, offs);
  // G2: hidden x w2t^T -> y (plain bf16 rows)
  moe_gemm_kernel<HDIM, DMODEL, false><<<MTILES * (DMODEL / BN), 256, 0, stream>>>(
      hidden, w2t, y, perm, offs);

  combine_kernel<<<T_TOKENS, 256, 0, stream>>>(y, t2r, wsv, bias, out);
}

// Round 8
// 191.952 us; speedup vs baseline: 2.2725x; 1.2376x over previous
//
#include <hip/hip_runtime.h>
#include <hip/hip_bf16.h>
#include <cmath>

// ---------------- problem constants ----------------
#define T_TOKENS 4096   // 2*2048
#define DMODEL   1024
#define HDIM     2048
#define NEXP     8
#define BM 128
#define BN 128
#define BK 64
#define MAXROWS 9216    // 8192 routed rows + worst-case per-expert padding to 128
#define MTILES  (MAXROWS / BM)   // 72

typedef __bf16 bf16;
typedef __bf16 bf16x8 __attribute__((ext_vector_type(8)));
typedef __bf16 bf16x4 __attribute__((ext_vector_type(4)));
typedef float  f32x4  __attribute__((ext_vector_type(4)));

__device__ inline void gload_lds16(const void* g, void* l) {
  __builtin_amdgcn_global_load_lds(
      (const __attribute__((address_space(1))) void*)g,
      (__attribute__((address_space(3))) void*)l, 16, 0, 0);
}

// ---------------- router: logits -> softmax -> top2; also x -> bf16 ----------------
// NO atomics (R6 PMC: 8192 same-line atomicAdds ~= 100us serialized).
__global__ __launch_bounds__(256) void router_kernel(
    const float* __restrict__ x, const float* __restrict__ gw,
    bf16* __restrict__ xb, int* __restrict__ es, float* __restrict__ wsv)
{
  int wid = threadIdx.x >> 6, lane = threadIdx.x & 63;
  int t = blockIdx.x * 4 + wid;
  if (t >= T_TOKENS) return;
  const float* xrow = x + (size_t)t * DMODEL;

  double acc[NEXP];
#pragma unroll
  for (int e = 0; e < NEXP; e++) acc[e] = 0.0;

#pragma unroll
  for (int i = 0; i < 4; i++) {
    int d0 = (i * 64 + lane) * 4;
    float4 xv = *(const float4*)(xrow + d0);
    bf16x4 o = { (bf16)xv.x, (bf16)xv.y, (bf16)xv.z, (bf16)xv.w };
    *(bf16x4*)(xb + (size_t)t * DMODEL + d0) = o;
    const float* g0 = gw + (size_t)d0 * NEXP;
    float xs[4] = { xv.x, xv.y, xv.z, xv.w };
#pragma unroll
    for (int j = 0; j < 4; j++)
#pragma unroll
      for (int e = 0; e < NEXP; e++)
        acc[e] += (double)xs[j] * (double)g0[j * NEXP + e];
  }
#pragma unroll
  for (int e = 0; e < NEXP; e++) {
    double v = acc[e];
#pragma unroll
    for (int m = 32; m >= 1; m >>= 1) v += __shfl_xor(v, m, 64);
    acc[e] = v;
  }
  if (lane == 0) {
    float l[NEXP], p[NEXP];
    float mx = -1e30f;
#pragma unroll
    for (int e = 0; e < NEXP; e++) { l[e] = (float)acc[e]; mx = fmaxf(mx, l[e]); }
    float s = 0.f;
#pragma unroll
    for (int e = 0; e < NEXP; e++) { p[e] = __expf(l[e] - mx); s += p[e]; }
#pragma unroll
    for (int e = 0; e < NEXP; e++) p[e] /= s;
    int i0 = 0;
#pragma unroll
    for (int e = 1; e < NEXP; e++) if (p[e] > p[i0]) i0 = e;
    int i1 = (i0 == 0) ? 1 : 0;
#pragma unroll
    for (int e = 0; e < NEXP; e++) if (e != i0 && p[e] > p[i1]) i1 = e;
    float wA = p[i0], wB = p[i1];
    float dn = wA + wB + 1e-9f;
    wA /= dn; wB /= dn;
    es[t] = i0; es[T_TOKENS + t] = i1;
    wsv[t] = wA; wsv[T_TOKENS + t] = wB;
  }
}

// ---------------- setup: histogram + offsets + deterministic assignment ----------
__global__ __launch_bounds__(256) void setup_kernel(
    const int* __restrict__ es, int* __restrict__ off,
    int* __restrict__ perm, int* __restrict__ t2r)
{
  __shared__ int hist[256 * NEXP];
  __shared__ int offL[NEXP + 1];
  int tid = threadIdx.x;

  for (int i = tid; i < MAXROWS; i += 256) perm[i] = -1;

  int h[NEXP];
#pragma unroll
  for (int e = 0; e < NEXP; e++) h[e] = 0;
  int base = tid * 32;
#pragma unroll
  for (int k = 0; k < 32; k++) {
    int ev = es[base + k];
#pragma unroll
    for (int e = 0; e < NEXP; e++) h[e] += (ev == e);
  }
#pragma unroll
  for (int e = 0; e < NEXP; e++) hist[tid * NEXP + e] = h[e];
  __syncthreads();

  if (tid < NEXP) {
    int s = 0;
    for (int t = 0; t < 256; t++) {
      int v = hist[t * NEXP + tid];
      hist[t * NEXP + tid] = s;
      s += v;
    }
    offL[tid] = s;
  }
  __syncthreads();
  if (tid == 0) {
    int o = 0;
    int tot[NEXP];
#pragma unroll
    for (int e = 0; e < NEXP; e++) tot[e] = offL[e];
#pragma unroll
    for (int e = 0; e < NEXP; e++) {
      offL[e] = o;
      off[e] = o;
      o += ((tot[e] + BM - 1) / BM) * BM;
    }
    offL[NEXP] = o;
    off[NEXP] = o;
  }
  __syncthreads();

  int run[NEXP];
#pragma unroll
  for (int e = 0; e < NEXP; e++) run[e] = offL[e] + hist[tid * NEXP + e];
#pragma unroll
  for (int k = 0; k < 32; k++) {
    int i = base + k;
    int ev = es[i];
    int row = 0;
#pragma unroll
    for (int e = 0; e < NEXP; e++) {
      if (ev == e) { row = run[e]; run[e] = row + 1; }
    }
    perm[row] = i & (T_TOKENS - 1);
    t2r[i] = row;
  }
}

// ---------------- weight fp32 [E][R][C] -> bf16 transposed [E][C][R] ----------------
__global__ __launch_bounds__(256) void transpose_cvt_kernel(
    const float* __restrict__ src, bf16* __restrict__ dst, int R, int C)
{
  __shared__ bf16 tile[64][66];
  int e = blockIdx.z;
  int r0 = blockIdx.y * 64, c0 = blockIdx.x * 64;
  const float* s = src + (size_t)e * R * C;
  bf16* d = dst + (size_t)e * R * C;
  int tr = threadIdx.x >> 4;
  int tc4 = (threadIdx.x & 15) * 4;
#pragma unroll
  for (int i = 0; i < 4; i++) {
    int r = tr + i * 16;
    float4 v = *(const float4*)(s + (size_t)(r0 + r) * C + c0 + tc4);
    tile[tc4 + 0][r] = (bf16)v.x;
    tile[tc4 + 1][r] = (bf16)v.y;
    tile[tc4 + 2][r] = (bf16)v.z;
    tile[tc4 + 3][r] = (bf16)v.w;
  }
  __syncthreads();
  int cc0 = threadIdx.x >> 3;
  int ch = (threadIdx.x & 7) * 8;
#pragma unroll
  for (int i = 0; i < 2; i++) {
    int cc = cc0 + i * 32;
    const unsigned int* rp = (const unsigned int*)&tile[cc][0];
    unsigned int u0 = rp[ch / 2 + 0];
    unsigned int u1 = rp[ch / 2 + 1];
    unsigned int u2 = rp[ch / 2 + 2];
    unsigned int u3 = rp[ch / 2 + 3];
    uint4 o = { u0, u1, u2, u3 };
    *(uint4*)(d + (size_t)(c0 + cc) * R + r0 + ch) = o;
  }
}

// ---------------- MFMA GEMM: expert-aligned XCD mapping + T2 swizzle ----------------
// Dispatch is XCD round-robin (XCD = bid % 8), so EXPERT = bid & 7: each
// expert's tiles run ONLY on its XCD -> per-XCD weight working set = that
// expert's 4 MB slab = exactly one L2. (R7 PMC: striped mt mapping made every
// XCD touch all 8 experts -> 36 MB/XCD working set -> L3-latency-bound at
// 2 TB/s, FETCH 141 MB.) r = bid>>3; nt = r & (NTN-1); mt_local = r >> log2NTN;
// idle-exit past the expert's dynamic row count (grid sized for worst case).
// 128x128x64 tile, 4 waves, single 32KB LDS buffer (~3-4 blocks/CU TLP —
// proven lever R6). XOR swizzle byte^=(row&7)<<4, pre-swizzled global source.
template<int KDIM, int NDIM, bool GELU>
__global__ __launch_bounds__(256) void moe_gemm_kernel(
    const bf16* __restrict__ A, const bf16* __restrict__ W,
    bf16* __restrict__ dst, const int* __restrict__ perm,
    const int* __restrict__ off)
{
  constexpr int NTN = NDIM / BN;           // 16 (G1) or 8 (G2)
  constexpr int LOG2NTN = (NTN == 16) ? 4 : 3;
  int e  = blockIdx.x & 7;                 // expert == XCD
  int r  = blockIdx.x >> 3;
  int nt = r & (NTN - 1);
  int mtl = r >> LOG2NTN;
  int rowbase = off[e];
  int nrows = off[e + 1] - rowbase;
  if (mtl * BM >= nrows) return;           // idle block (imbalance slack)
  int row0 = rowbase + mtl * BM;
  int n0 = nt * BN;
  const bf16* Wb = W + (size_t)e * NDIM * KDIM;

  __shared__ bf16 As[BM * BK];
  __shared__ bf16 Bs[BN * BK];

  int tid = threadIdx.x;
  int lane = tid & 63;
  int wid = tid >> 6;
  int wm = wid >> 1, wn = wid & 1;
  int l15 = lane & 15;
  int hi16 = (lane >> 4) << 4;

  int sr = tid >> 3;                       // staging row 0..31 (+32i)
  int sc8 = tid & 7;                       // LDS 16B slot
  int scol = (sc8 ^ (sr & 7)) * 8;         // inverse-swizzled global col (elems)

  unsigned arow[4];
#pragma unroll
  for (int i = 0; i < 4; i++) {
    int rr = sr + i * 32;
    unsigned g;
    if (GELU) { int p = perm[row0 + rr]; g = (p < 0) ? 0u : (unsigned)p; }
    else      { g = (unsigned)(row0 + rr); }
    arow[i] = g * (unsigned)KDIM;
  }
  unsigned brow[4];
#pragma unroll
  for (int i = 0; i < 4; i++) brow[i] = (unsigned)(n0 + sr + i * 32) * KDIM;

  f32x4 acc[4][4];
#pragma unroll
  for (int m = 0; m < 4; m++)
#pragma unroll
    for (int n = 0; n < 4; n++) acc[m][n] = (f32x4){0.f, 0.f, 0.f, 0.f};

  for (int k0 = 0; k0 < KDIM; k0 += BK) {
#pragma unroll
    for (int i = 0; i < 4; i++)
      gload_lds16(A + arow[i] + k0 + scol, &As[((sr + i * 32) * BK) + sc8 * 8]);
#pragma unroll
    for (int i = 0; i < 4; i++)
      gload_lds16(Wb + brow[i] + k0 + scol, &Bs[((sr + i * 32) * BK) + sc8 * 8]);
    asm volatile("s_waitcnt vmcnt(0)" ::: "memory");
    __syncthreads();

    const char* asB = (const char*)As;
    const char* bsB = (const char*)Bs;
#pragma unroll
    for (int kk = 0; kk < 2; kk++) {
      int kb = kk * 64 + hi16;             // byte col within 128B row
      bf16x8 af[4], bfr[4];
#pragma unroll
      for (int m = 0; m < 4; m++) {
        int rr = wm * 64 + m * 16 + l15;
        af[m] = *(const bf16x8*)(asB + rr * 128 + (kb ^ ((rr & 7) << 4)));
      }
#pragma unroll
      for (int n = 0; n < 4; n++) {
        int rr = wn * 64 + n * 16 + l15;
        bfr[n] = *(const bf16x8*)(bsB + rr * 128 + (kb ^ ((rr & 7) << 4)));
      }
#pragma unroll
      for (int m = 0; m < 4; m++)
#pragma unroll
        for (int n = 0; n < 4; n++)
          acc[m][n] = __builtin_amdgcn_mfma_f32_16x16x32_bf16(af[m], bfr[n], acc[m][n], 0, 0, 0);
    }
    __syncthreads();
  }

  // epilogue: C/D layout col = lane&15, row = (lane>>4)*4 + j2 ; bf16 store
#pragma unroll
  for (int m = 0; m < 4; m++) {
    int rbase = row0 + wm * 64 + m * 16 + ((lane >> 4) << 2);
#pragma unroll
    for (int j2 = 0; j2 < 4; j2++) {
      unsigned rg = (unsigned)(rbase + j2);
#pragma unroll
      for (int n = 0; n < 4; n++) {
        float v = acc[m][n][j2];
        if (GELU) v = 0.5f * v * (1.0f + erff(v * 0.70710678118654752f));
        dst[(size_t)rg * NDIM + (n0 + wn * 64 + n * 16 + l15)] = (bf16)v;
      }
    }
  }
}

// ---------------- combine: out = bias + w0*y[r0] + w1*y[r1] ----------------
__global__ __launch_bounds__(256) void combine_kernel(
    const bf16* __restrict__ y, const int* __restrict__ t2r,
    const float* __restrict__ wsv, const float* __restrict__ bias,
    float* __restrict__ out)
{
  int t = blockIdx.x;
  int d = threadIdx.x * 4;
  int r0 = t2r[t], r1 = t2r[T_TOKENS + t];
  float w0 = wsv[t], w1 = wsv[T_TOKENS + t];
  bf16x4 a = *(const bf16x4*)(y + (size_t)r0 * DMODEL + d);
  bf16x4 b = *(const bf16x4*)(y + (size_t)r1 * DMODEL + d);
  float4 bs = *(const float4*)(bias + d);
  float4 o;
  o.x = bs.x + w0 * (float)a[0] + w1 * (float)b[0];
  o.y = bs.y + w0 * (float)a[1] + w1 * (float)b[1];
  o.z = bs.z + w0 * (float)a[2] + w1 * (float)b[2];
  o.w = bs.w + w0 * (float)a[3] + w1 * (float)b[3];
  *(float4*)(out + (size_t)t * DMODEL + d) = o;
}

// ---------------- host ----------------
extern "C" void kernel_launch(void* const* d_in, const int* in_sizes, int n_in,
                              void* d_out, int out_size, void* d_ws, size_t ws_size,
                              hipStream_t stream)
{
  const float* x    = (const float*)d_in[0];
  const float* gw   = (const float*)d_in[1];
  const float* w1   = (const float*)d_in[2];
  const float* w2   = (const float*)d_in[3];
  const float* bias = (const float*)d_in[4];
  float* out = (float*)d_out;

  char* ws = (char*)d_ws;
  size_t o = 0;
  auto alloc = [&](size_t bytes) {
    void* p = ws + o;
    o = (o + bytes + 255) & ~(size_t)255;
    return p;
  };
  bf16*  xb     = (bf16*) alloc((size_t)T_TOKENS * DMODEL * 2);       // 8 MB
  bf16*  w1t    = (bf16*) alloc((size_t)NEXP * HDIM * DMODEL * 2);    // 32 MB [E][H][D]
  bf16*  w2t    = (bf16*) alloc((size_t)NEXP * DMODEL * HDIM * 2);    // 32 MB [E][D][H]
  bf16*  hidden = (bf16*) alloc((size_t)MAXROWS * HDIM * 2);          // 37.7 MB
  int*   perm   = (int*)  alloc((size_t)MAXROWS * 4);
  int*   t2r    = (int*)  alloc((size_t)2 * T_TOKENS * 4);
  int*   es     = (int*)  alloc((size_t)2 * T_TOKENS * 4);
  float* wsv    = (float*)alloc((size_t)2 * T_TOKENS * 4);
  int*   offs   = (int*)  alloc(64);
  // y aliases w1t: w1t is dead after G1; G2 writes y before combine reads it.
  bf16*  y      = w1t;   // MAXROWS*DMODEL*2 = 18.9 MB <= 32 MB

  router_kernel<<<T_TOKENS / 4, 256, 0, stream>>>(x, gw, xb, es, wsv);
  setup_kernel<<<1, 256, 0, stream>>>(es, offs, perm, t2r);

  // w1 [E][D][H] -> w1t [E][H][D]
  transpose_cvt_kernel<<<dim3(HDIM / 64, DMODEL / 64, NEXP), 256, 0, stream>>>(w1, w1t, DMODEL, HDIM);
  // w2 [E][H][D] -> w2t [E][D][H]
  transpose_cvt_kernel<<<dim3(DMODEL / 64, HDIM / 64, NEXP), 256, 0, stream>>>(w2, w2t, HDIM, DMODEL);

  // G1: xb(perm rows) x w1t^T -> gelu -> hidden ; grid covers worst-case imbalance
  moe_gemm_kernel<DMODEL, HDIM, true><<<NEXP * MTILES * (HDIM / BN), 256, 0, stream>>>(
      xb, w1t, hidden, perm, offs);
  // G2: hidden x w2t^T -> y (plain bf16 rows)
  moe_gemm_kernel<HDIM, DMODEL, false><<<NEXP * MTILES * (DMODEL / BN), 256, 0, stream>>>(
      hidden, w2t, y, perm, offs);

  combine_kernel<<<T_TOKENS, 256, 0, stream>>>(y, t2r, wsv, bias, out);
}